// Round 10
// baseline (214.249 us; speedup 1.0000x reference)
//
#include <hip/hip_runtime.h>
#include <hip/hip_bf16.h>

// ALiBi causal attention, B=2 T=2048 C=1024 H=16 D=64. Inputs fp32, output fp32.
// Round 10: attn kv-split wave groups: 512 thr = 2 groups x 4 q-waves over the
// same 128q x 128kv tile; group g computes 64-kv half g of each stage. Static-
// max softmax makes partial (O,l) additive -> cheap LDS add-merge at the end.
// Waves/CU 8 -> 16. GEMMs (dbuf, 1 barrier) and cvt unchanged from round 9.

typedef _Float16 f16;
typedef f16 f16x2 __attribute__((ext_vector_type(2)));
typedef f16 f16x4 __attribute__((ext_vector_type(4)));
typedef f16 f16x8 __attribute__((ext_vector_type(8)));
typedef float f32x4 __attribute__((ext_vector_type(4)));
typedef float f32x16 __attribute__((ext_vector_type(16)));

#define LOG2E 1.4426950408889634f
#define LDK 40   // GEMM LDS stride (halves): 80B rows; write/read <=2-way banks
#define LDA 72   // attn K-tile stride (halves): 144B rows, b128-aligned
#define LDV 136  // attn V^T-tile stride (halves): 272B rows, b128-aligned

__device__ __forceinline__ f16x4 pk4(f32x4 v) {
  f16x2 a = __builtin_bit_cast(f16x2, __builtin_amdgcn_cvt_pkrtz(v[0], v[1]));
  f16x2 b = __builtin_bit_cast(f16x2, __builtin_amdgcn_cvt_pkrtz(v[2], v[3]));
  f16x4 r; r[0] = a[0]; r[1] = a[1]; r[2] = b[0]; r[3] = b[1];
  return r;
}
// pack P fragment p from ev[16]: slots 0..3 = ev[4p..], 4..7 = ev[8+4p..]
__device__ __forceinline__ f16x8 mkp(const float* e, int p) {
  f16x2 a = __builtin_bit_cast(f16x2, __builtin_amdgcn_cvt_pkrtz(e[4*p+0], e[4*p+1]));
  f16x2 b = __builtin_bit_cast(f16x2, __builtin_amdgcn_cvt_pkrtz(e[4*p+2], e[4*p+3]));
  f16x2 c = __builtin_bit_cast(f16x2, __builtin_amdgcn_cvt_pkrtz(e[8+4*p+0], e[8+4*p+1]));
  f16x2 d = __builtin_bit_cast(f16x2, __builtin_amdgcn_cvt_pkrtz(e[8+4*p+2], e[8+4*p+3]));
  f16x8 r;
  r[0]=a[0]; r[1]=a[1]; r[2]=b[0]; r[3]=b[1];
  r[4]=c[0]; r[5]=c[1]; r[6]=d[0]; r[7]=d[1];
  return r;
}

// ----------------------------------------------------------------- cvt kernel
__global__ __launch_bounds__(256) void cvt_f32_f16(
    const float* __restrict__ x, const float* __restrict__ wq,
    const float* __restrict__ wk, const float* __restrict__ wv,
    const float* __restrict__ wo,
    f16* __restrict__ dx, f16* __restrict__ dwq, f16* __restrict__ dwk,
    f16* __restrict__ dwv, f16* __restrict__ dwo) {
  const float* src; f16* dst; int n;
  switch (blockIdx.y) {
    case 0:  src = x;  dst = dx;  n = 4194304; break;
    case 1:  src = wq; dst = dwq; n = 1048576; break;
    case 2:  src = wk; dst = dwk; n = 1048576; break;
    case 3:  src = wv; dst = dwv; n = 1048576; break;
    default: src = wo; dst = dwo; n = 1048576; break;
  }
  int i = (blockIdx.x * 256 + (int)threadIdx.x) * 8;
  if (i >= n) return;
  f32x4 a = *(const f32x4*)(src + i);
  f32x4 b = *(const f32x4*)(src + i + 4);
  f16x8 o;
  f16x4 lo4 = pk4(a), hi4 = pk4(b);
#pragma unroll
  for (int j = 0; j < 4; j++) { o[j] = lo4[j]; o[j + 4] = hi4[j]; }
  *(f16x8*)(dst + i) = o;
}

// ---------------------------------------------- GEMM core (dbuf, 1 barrier)
__device__ __forceinline__ void gemm_core(const f16* __restrict__ A,
                                          const f16* __restrict__ W,
                                          int m0, int n0,
                                          f16* lA, f16* lW,  // each 2*128*LDK
                                          f32x4 acc[4][4]) {
  const int tid = threadIdx.x;
  const int lane = tid & 63, w = tid >> 6;
  const int wm = w & 1, wn = w >> 1;
  const int q = lane & 15, quad = lane >> 4;
  const int r0 = tid >> 2, c0 = (tid & 3) * 8;  // staging: rows {r0, r0+64}

  const f16* Ap = A + (m0 + r0) * 1024 + c0;
  const f16* Wp = W + (n0 + r0) * 1024 + c0;
  f16x8 a0 = *(const f16x8*)(Ap);
  f16x8 a1 = *(const f16x8*)(Ap + 64 * 1024);
  f16x8 w0 = *(const f16x8*)(Wp);
  f16x8 w1 = *(const f16x8*)(Wp + 64 * 1024);

#pragma unroll 2
  for (int r = 0; r < 32; r++) {
    const int p = r & 1;
    f16* dA = lA + p * (128 * LDK);
    f16* dW = lW + p * (128 * LDK);
    *(f16x8*)(dA + r0 * LDK + c0) = a0;
    *(f16x8*)(dA + (64 + r0) * LDK + c0) = a1;
    *(f16x8*)(dW + r0 * LDK + c0) = w0;
    *(f16x8*)(dW + (64 + r0) * LDK + c0) = w1;
    if (r + 1 < 32) {
      const int kn = (r + 1) * 32;
      a0 = *(const f16x8*)(Ap + kn);
      a1 = *(const f16x8*)(Ap + 64 * 1024 + kn);
      w0 = *(const f16x8*)(Wp + kn);
      w1 = *(const f16x8*)(Wp + 64 * 1024 + kn);
    }
    __syncthreads();
    f16x8 aF[4], bF[4];
#pragma unroll
    for (int mt = 0; mt < 4; mt++)
      aF[mt] = *(const f16x8*)(dA + (wm * 64 + mt * 16 + q) * LDK + quad * 8);
#pragma unroll
    for (int nt = 0; nt < 4; nt++)
      bF[nt] = *(const f16x8*)(dW + (wn * 64 + nt * 16 + q) * LDK + quad * 8);
#pragma unroll
    for (int mt = 0; mt < 4; mt++)
#pragma unroll
      for (int nt = 0; nt < 4; nt++)
        acc[mt][nt] = __builtin_amdgcn_mfma_f32_16x16x32_f16(aF[mt], bF[nt], acc[mt][nt], 0, 0, 0);
  }
}

// ------------------------------------------------------------ QKV projection
__global__ __launch_bounds__(256) void qkv_proj(
    const f16* __restrict__ x16, const f16* __restrict__ wq16,
    const f16* __restrict__ wk16, const f16* __restrict__ wv16,
    f16* __restrict__ qb, f16* __restrict__ kb, f16* __restrict__ vb,
    float qscale) {
  __shared__ __align__(16) f16 lA[2 * 128 * LDK];
  __shared__ __align__(16) f16 lW[2 * 128 * LDK];
  const int m0 = blockIdx.x * 128, n0 = blockIdx.y * 128;
  const int z = blockIdx.z;
  const f16* W = (z == 0) ? wq16 : (z == 1) ? wk16 : wv16;
  f16* out = (z == 0) ? qb : (z == 1) ? kb : vb;
  const float scale = (z == 0) ? qscale : 1.0f;

  f32x4 acc[4][4];
  const f32x4 zero = {0.f, 0.f, 0.f, 0.f};
#pragma unroll
  for (int i = 0; i < 4; i++)
#pragma unroll
    for (int j = 0; j < 4; j++) acc[i][j] = zero;
  gemm_core(x16, W, m0, n0, lA, lW, acc);

  const int tid = threadIdx.x, lane = tid & 63, w = tid >> 6;
  const int wm = w & 1, wn = w >> 1, q = lane & 15, quad = lane >> 4;
#pragma unroll
  for (int mt = 0; mt < 4; mt++)
#pragma unroll
    for (int nt = 0; nt < 4; nt++) {
      int n = n0 + wn * 64 + nt * 16 + q;
      int h = n >> 6, d = n & 63;
#pragma unroll
      for (int r = 0; r < 4; r++) {
        int mm = m0 + wm * 64 + mt * 16 + quad * 4 + r;
        int bb = mm >> 11, tl = mm & 2047;
        out[((bb * 16 + h) * 2048 + tl) * 64 + d] = (f16)(acc[mt][nt][r] * scale);
      }
    }
}

// --------------------------------------------------------------- attention
// grid (32 bh, 16 tiles): qb_ = 15 - y (long first). 512 thr = 8 waves =
// 2 kv-groups x 4 q-waves; wave (grp,wg) owns 32 q rows and 64-kv half grp of
// each 128-kv stage. 32x32x16 MFMA, permuted K staging (QK^T C-regs feed PV
// B-operand), static-max softmax (-8 C-init) => additive partials; group 1's
// (O,l) merged into group 0 via LDS adds at the end.
__global__ __launch_bounds__(512, 4) void attn(
    const f16* __restrict__ qB, const f16* __restrict__ kB,
    const f16* __restrict__ vB, f16* __restrict__ att) {
  __shared__ __align__(16) char SM[36864];
  f16* lK = (f16*)SM;                 // [kv(perm)][d] 128*72*2 = 18432 B
  f16* lV = (f16*)(SM + 18432);       // [d][kv]       64*136*2 = 17408 B
  float* mgO = (float*)SM;            // merge: 128 q x 68 f32 (dead lK/lV)
  float* mgL = (float*)(SM + 34816);  // merge: 256 f32

  const int tid = threadIdx.x, lane = tid & 63, w = tid >> 6;
  const int wg = w & 3, grp = w >> 2;
  const int n5 = lane & 31, hh = lane >> 5;
  const int bh = blockIdx.x, qb_ = 15 - (int)blockIdx.y;
  const int b = bh >> 4, h = bh & 15;
  const int q0 = qb_ * 128;
  const f16* qP = qB + (bh * 2048) * 64;
  const f16* kP = kB + (bh * 2048) * 64;
  const f16* vP = vB + (bh * 2048) * 64;

  const float slope2 = __builtin_amdgcn_exp2f(-0.5f * (float)(h + 1)) * LOG2E;
  const int qg = q0 + wg * 32 + n5;              // this lane's q row (C col)
  const int qlast = q0 + wg * 32 + 31;           // wave's last q row
  const int wdiag = ((q0 + wg * 32) >> 6) << 6;  // 64-half holding wave's diag

  f16x8 qF[4];  // B-operand: B[k = ks*16 + hh*8 + j][n = qg]
#pragma unroll
  for (int ks = 0; ks < 4; ks++)
    qF[ks] = *(const f16x8*)(qP + qg * 64 + ks * 16 + hh * 8);

  f32x16 cinit, ot0, ot1;
#pragma unroll
  for (int i = 0; i < 16; i++) { cinit[i] = -8.0f; ot0[i] = 0.f; ot1[i] = 0.f; }
  float lsum = 0.0f;

  // K staging (512 thr): thread -> rows {kr, kr+64}, col seg ks8; row permuted.
  const int kr = tid >> 3, ks8 = (tid & 7) * 8;
  const int pp = kr & 31;
  const int mperm = (pp & 3) + 16 * ((pp >> 2) & 1) + 4 * ((pp >> 3) & 1) + 8 * ((pp >> 4) & 1);
  const int lkr = (kr & 32) + mperm;
  // V staging: kv pair vp, d seg vd (= wave id * 8); transpose to lV[d][kv].
  const int vp = (tid & 63) * 2, vd = (tid >> 6) * 8;

  f16x8 kA, kB_, vA, vB_;
  kA  = *(const f16x8*)(kP + kr * 64 + ks8);
  kB_ = *(const f16x8*)(kP + (64 + kr) * 64 + ks8);
  vA  = *(const f16x8*)(vP + vp * 64 + vd);
  vB_ = *(const f16x8*)(vP + (vp + 1) * 64 + vd);

  const int nstage = qb_ + 1;
  for (int stg = 0; stg < nstage; stg++) {
    const int kv0 = stg << 7;
    __syncthreads();
    *(f16x8*)(lK + lkr * LDA + ks8) = kA;
    *(f16x8*)(lK + (64 + lkr) * LDA + ks8) = kB_;
#pragma unroll
    for (int j = 0; j < 8; j++) {
      f16x2 t; t[0] = vA[j]; t[1] = vB_[j];
      *(f16x2*)(lV + (vd + j) * LDV + vp) = t;
    }
    __syncthreads();
    if (stg + 1 < nstage) {
      const int kn = kv0 + 128;
      kA  = *(const f16x8*)(kP + (kn + kr) * 64 + ks8);
      kB_ = *(const f16x8*)(kP + (kn + 64 + kr) * 64 + ks8);
      vA  = *(const f16x8*)(vP + (kn + vp) * 64 + vd);
      vB_ = *(const f16x8*)(vP + (kn + vp + 1) * 64 + vd);
    }
    const int kvh = kv0 + grp * 64;  // this group's 64-kv half
    if (kvh <= wdiag) {
      const bool act1 = (kvh + 32 <= qlast);     // upper 32-kv tile live?
      const bool needmask = (kvh == wdiag);
      // S^T = K.Q^T, C-init = -8 (static max)
      f32x16 s0 = cinit, s1 = cinit;
#pragma unroll
      for (int ks = 0; ks < 4; ks++) {
        f16x8 kf = *(const f16x8*)(lK + (grp * 64 + n5) * LDA + ks * 16 + hh * 8);
        s0 = __builtin_amdgcn_mfma_f32_32x32x16_f16(kf, qF[ks], s0, 0, 0, 0);
      }
      if (act1) {
#pragma unroll
        for (int ks = 0; ks < 4; ks++) {
          f16x8 kf = *(const f16x8*)(lK + (grp * 64 + 32 + n5) * LDA + ks * 16 + hh * 8);
          s1 = __builtin_amdgcn_mfma_f32_32x32x16_f16(kf, qF[ks], s1, 0, 0, 0);
        }
      }
      // bias + mask + exp2. Element (reg=t+4u, hh) = physical kv offset
      // CR + 8*hh within its 32-tile, CR = 16*(u&1) + 4*(u>>1) + t.
      f16x8 pf00, pf01, pf10, pf11;
      {
        const int dQ = qg - kvh - 8 * hh;
        const float base0 = -slope2 * (float)dQ;
        float ev[16];
#pragma unroll
        for (int u = 0; u < 4; u++)
#pragma unroll
          for (int t = 0; t < 4; t++) {
            const int reg = t + 4 * u;
            const int CR = 16 * (u & 1) + 4 * (u >> 1) + t;
            float val = s0[reg] + fmaf(slope2, (float)CR, base0);
            if (needmask) val = (dQ >= CR) ? val : -1e30f;
            float e = __builtin_amdgcn_exp2f(val);
            lsum += e;
            ev[reg] = e;
          }
        pf00 = mkp(ev, 0); pf01 = mkp(ev, 1);
        if (act1) {
          const int dQ1 = dQ - 32;
          const float base1 = -slope2 * (float)dQ1;
          float ev1[16];
#pragma unroll
          for (int u = 0; u < 4; u++)
#pragma unroll
            for (int t = 0; t < 4; t++) {
              const int reg = t + 4 * u;
              const int CR = 16 * (u & 1) + 4 * (u >> 1) + t;
              float val = s1[reg] + fmaf(slope2, (float)CR, base1);
              if (needmask) val = (dQ1 >= CR) ? val : -1e30f;
              float e = __builtin_amdgcn_exp2f(val);
              lsum += e;
              ev1[reg] = e;
            }
          pf10 = mkp(ev1, 0); pf11 = mkp(ev1, 1);
        }
      }
      // O^T += V^T . P^T  (A = V^T b128 reads, contiguous physical kv)
#pragma unroll
      for (int p = 0; p < 2; p++) {
        f16x8 vf0 = *(const f16x8*)(lV + n5 * LDV + grp * 64 + p * 16 + hh * 8);
        f16x8 vf1 = *(const f16x8*)(lV + (32 + n5) * LDV + grp * 64 + p * 16 + hh * 8);
        f16x8 pf = p ? pf01 : pf00;
        ot0 = __builtin_amdgcn_mfma_f32_32x32x16_f16(vf0, pf, ot0, 0, 0, 0);
        ot1 = __builtin_amdgcn_mfma_f32_32x32x16_f16(vf1, pf, ot1, 0, 0, 0);
      }
      if (act1) {
#pragma unroll
        for (int p = 0; p < 2; p++) {
          f16x8 vf0 = *(const f16x8*)(lV + n5 * LDV + grp * 64 + 32 + p * 16 + hh * 8);
          f16x8 vf1 = *(const f16x8*)(lV + (32 + n5) * LDV + grp * 64 + 32 + p * 16 + hh * 8);
          f16x8 pf = p ? pf11 : pf10;
          ot0 = __builtin_amdgcn_mfma_f32_32x32x16_f16(vf0, pf, ot0, 0, 0, 0);
          ot1 = __builtin_amdgcn_mfma_f32_32x32x16_f16(vf1, pf, ot1, 0, 0, 0);
        }
      }
    }
  }

  // combine hh halves of l (per q col), then merge groups (static max => add)
  lsum += __shfl_xor(lsum, 32);
  __syncthreads();  // all loop LDS reads done; lK/lV reusable as merge scratch
  if (grp == 1) {
#pragma unroll
    for (int dt = 0; dt < 2; dt++)
#pragma unroll
      for (int u = 0; u < 4; u++) {
        f32x4 v4;
#pragma unroll
        for (int t = 0; t < 4; t++) v4[t] = (dt ? ot1[t + 4 * u] : ot0[t + 4 * u]);
        *(f32x4*)(mgO + (wg * 32 + n5) * 68 + dt * 32 + 8 * u + 4 * hh) = v4;
      }
    mgL[wg * 64 + lane] = lsum;
  }
  __syncthreads();
  float inv = 0.0f;
  if (grp == 0) {
    lsum += mgL[wg * 64 + lane];
    inv = 1.0f / lsum;
#pragma unroll
    for (int dt = 0; dt < 2; dt++)
#pragma unroll
      for (int u = 0; u < 4; u++) {
        f32x4 v4 = *(const f32x4*)(mgO + (wg * 32 + n5) * 68 + dt * 32 + 8 * u + 4 * hh);
#pragma unroll
        for (int t = 0; t < 4; t++) {
          if (dt) ot1[t + 4 * u] += v4[t];
          else    ot0[t + 4 * u] += v4[t];
        }
      }
  }
  __syncthreads();  // mg reads complete before OT overwrite
  if (grp == 0) {
    f16* OT = lK + wg * (32 * LDA);
#pragma unroll
    for (int dt = 0; dt < 2; dt++)
#pragma unroll
      for (int u = 0; u < 4; u++) {
        f16x4 o4;
#pragma unroll
        for (int t = 0; t < 4; t++) {
          float v = (dt ? ot1[t + 4 * u] : ot0[t + 4 * u]) * inv;
          o4[t] = (f16)v;
        }
        // d = dt*32 + 8u + 4hh + t
        *(f16x4*)(OT + n5 * LDA + dt * 32 + 8 * u + 4 * hh) = o4;
      }
  }
  __syncthreads();
  if (grp == 0) {
    const int row = lane >> 1, hr = lane & 1;
    const f16* OR = lK + wg * (32 * LDA) + row * LDA + hr * 32;
    f16* dst = att + (b * 2048 + q0 + wg * 32 + row) * 1024 + h * 64 + hr * 32;
#pragma unroll
    for (int j = 0; j < 4; j++)
      *(f16x8*)(dst + j * 8) = *(const f16x8*)(OR + j * 8);
  }
}

// ---------------------------------------------------------- output projection
__global__ __launch_bounds__(256) void out_proj(
    const f16* __restrict__ att, const f16* __restrict__ wo16,
    float* __restrict__ out) {
  __shared__ __align__(16) f16 lA[2 * 128 * LDK];
  __shared__ __align__(16) f16 lW[2 * 128 * LDK];
  const int m0 = blockIdx.x * 128, n0 = blockIdx.y * 128;
  f32x4 acc[4][4];
  const f32x4 zero = {0.f, 0.f, 0.f, 0.f};
#pragma unroll
  for (int i = 0; i < 4; i++)
#pragma unroll
    for (int j = 0; j < 4; j++) acc[i][j] = zero;
  gemm_core(att, wo16, m0, n0, lA, lW, acc);

  const int tid = threadIdx.x, lane = tid & 63, w = tid >> 6;
  const int wm = w & 1, wn = w >> 1, q = lane & 15, quad = lane >> 4;
#pragma unroll
  for (int mt = 0; mt < 4; mt++)
#pragma unroll
    for (int nt = 0; nt < 4; nt++) {
      int n = n0 + wn * 64 + nt * 16 + q;
#pragma unroll
      for (int r = 0; r < 4; r++) {
        int mm = m0 + wm * 64 + mt * 16 + quad * 4 + r;
        out[mm * 1024 + n] = acc[mt][nt][r];
      }
    }
}

// ------------------------------------------------------------------- launch
extern "C" void kernel_launch(void* const* d_in, const int* in_sizes, int n_in,
                              void* d_out, int out_size, void* d_ws, size_t ws_size,
                              hipStream_t stream) {
  const float* x  = (const float*)d_in[0];
  const float* Wq = (const float*)d_in[1];
  const float* Wk = (const float*)d_in[2];
  const float* Wv = (const float*)d_in[3];
  const float* Wo = (const float*)d_in[4];
  char* ws = (char*)d_ws;
  const size_t MB = 1024 * 1024;
  f16* x16  = (f16*)(ws);             // 8 MB; dead after qkv -> reused as att
  f16* qb   = (f16*)(ws + 8 * MB);    // (B,H,T,D) f16, 8 MB each
  f16* kb   = (f16*)(ws + 16 * MB);
  f16* vb   = (f16*)(ws + 24 * MB);
  f16* wq16 = (f16*)(ws + 32 * MB);   // 2 MB each
  f16* wk16 = (f16*)(ws + 34 * MB);
  f16* wv16 = (f16*)(ws + 36 * MB);
  f16* wo16 = (f16*)(ws + 38 * MB);   // total 40 MB
  f16* att  = x16;                    // overlay

  cvt_f32_f16<<<dim3(2048, 5), 256, 0, stream>>>(x, Wq, Wk, Wv, Wo,
                                                 x16, wq16, wk16, wv16, wo16);
  qkv_proj<<<dim3(32, 8, 3), 256, 0, stream>>>(x16, wq16, wk16, wv16,
                                               qb, kb, vb, 0.125f * LOG2E);
  attn<<<dim3(32, 16), 512, 0, stream>>>(qb, kb, vb, att);
  out_proj<<<dim3(32, 8), 256, 0, stream>>>(att, wo16, (float*)d_out);
}